// Round 3
// baseline (1918.564 us; speedup 1.0000x reference)
//
#include <hip/hip_runtime.h>
#include <stdint.h>

typedef unsigned short u16;
typedef __attribute__((ext_vector_type(8))) short short8;
typedef __attribute__((ext_vector_type(4))) float floatx4;
typedef __attribute__((ext_vector_type(4))) unsigned short u16x4;

#define T_TOK 2048
#define NHEAD 32

__device__ __forceinline__ float bf2f(u16 u) { return __uint_as_float(((unsigned)u) << 16); }
__device__ __forceinline__ u16 f2bf(float f) {
    unsigned u = __float_as_uint(f);
    return (u16)((u + 0x7fffu + ((u >> 16) & 1u)) >> 16);
}

__device__ __forceinline__ floatx4 mfma16(short8 a, short8 b, floatx4 c) {
    return __builtin_amdgcn_mfma_f32_16x16x32_bf16(a, b, c, 0, 0, 0);
}

// ---------------------------------------------------------------------------
// Generic bf16 GEMM, C = A @ B^T.  A: M x K (lda), B: N x K (ldb), C: M x N.
// m97 structure: 128x128 tile, BK=32, global_load_lds width 16, 16x16x32 MFMA.
// ---------------------------------------------------------------------------
__global__ __launch_bounds__(256) void gemm_bt(
    const u16* __restrict__ A, const u16* __restrict__ B, void* __restrict__ Cp,
    int M, int N, int K, int lda, int ldb, int ldc,
    long sA, long sB, long sC, int c_bf16)
{
    __shared__ u16 As[128 * 32];
    __shared__ u16 Bs[128 * 32];
    const int z = blockIdx.z;
    A += (long)z * sA;
    B += (long)z * sB;
    const int tid  = threadIdx.x;
    const int wave = tid >> 6;
    const int lane = tid & 63;
    const long m0 = (long)blockIdx.y * 128;
    const long n0 = (long)blockIdx.x * 128;
    const int wm = (wave & 1) * 64;
    const int wn = (wave >> 1) * 64;
    const int lr = lane & 15;
    const int lk = (lane >> 4) * 8;

    const u16* Ag = A + (m0 + (tid >> 2)) * (long)lda + (tid & 3) * 8;
    const u16* Bg = B + (n0 + (tid >> 2)) * (long)ldb + (tid & 3) * 8;
    const long a64 = (long)64 * lda, b64 = (long)64 * ldb;

    floatx4 acc[4][4] = {};

    for (int k0 = 0; k0 < K; k0 += 32) {
        __syncthreads();
        __builtin_amdgcn_global_load_lds(
            (const __attribute__((address_space(1))) void*)(Ag + k0),
            (__attribute__((address_space(3))) void*)(As + wave * 512), 16, 0, 0);
        __builtin_amdgcn_global_load_lds(
            (const __attribute__((address_space(1))) void*)(Ag + k0 + a64),
            (__attribute__((address_space(3))) void*)(As + 2048 + wave * 512), 16, 0, 0);
        __builtin_amdgcn_global_load_lds(
            (const __attribute__((address_space(1))) void*)(Bg + k0),
            (__attribute__((address_space(3))) void*)(Bs + wave * 512), 16, 0, 0);
        __builtin_amdgcn_global_load_lds(
            (const __attribute__((address_space(1))) void*)(Bg + k0 + b64),
            (__attribute__((address_space(3))) void*)(Bs + 2048 + wave * 512), 16, 0, 0);
        __syncthreads();
        short8 af[4], bfr[4];
#pragma unroll
        for (int t = 0; t < 4; t++) {
            af[t]  = *(const short8*)&As[(wm + t * 16 + lr) * 32 + lk];
            bfr[t] = *(const short8*)&Bs[(wn + t * 16 + lr) * 32 + lk];
        }
#pragma unroll
        for (int mt = 0; mt < 4; mt++)
#pragma unroll
            for (int nt = 0; nt < 4; nt++)
                acc[mt][nt] = mfma16(af[mt], bfr[nt], acc[mt][nt]);
    }

    const int rbase = wm + (lane >> 4) * 4;
    if (c_bf16) {
        u16* C = (u16*)Cp + (long)z * sC;
#pragma unroll
        for (int mt = 0; mt < 4; mt++)
#pragma unroll
            for (int nt = 0; nt < 4; nt++)
#pragma unroll
                for (int r = 0; r < 4; r++) {
                    long row = m0 + rbase + mt * 16 + r;
                    long col = n0 + wn + nt * 16 + lr;
                    C[row * ldc + col] = f2bf(acc[mt][nt][r]);
                }
    } else {
        float* C = (float*)Cp + (long)z * sC;
#pragma unroll
        for (int mt = 0; mt < 4; mt++)
#pragma unroll
            for (int nt = 0; nt < 4; nt++)
#pragma unroll
                for (int r = 0; r < 4; r++) {
                    long row = m0 + rbase + mt * 16 + r;
                    long col = n0 + wn + nt * 16 + lr;
                    C[row * ldc + col] = acc[mt][nt][r];
                }
    }
}

// ---------------------------------------------------------------------------
// Fused causal MLA attention. One block = (head, 64-row Q tile), 4 waves.
// Q frags persistent in VGPRs; K/V B-frags direct from L2-resident global;
// raw-exp softmax (no max subtraction — scaled logits are O(1) here), row sums
// in registers, single divide at the end.  S wave grid 2m x 2n; PV 1m x 4n.
// ---------------------------------------------------------------------------
#define P_LD 68
#define ESCALE 0.10411754f   // (1/sqrt(192)) * log2(e)

__global__ __launch_bounds__(256, 1) void flash_attn(
    const u16* __restrict__ Qp, const u16* __restrict__ Kp,
    const u16* __restrict__ cmpT, u16* __restrict__ o_lat)
{
    __shared__ u16 Ps[64 * P_LD];
    __shared__ float ex[2][64];

    const int qt = blockIdx.x;
    const int h  = blockIdx.y;
    const int qb = qt * 64;
    const int tid = threadIdx.x, wave = tid >> 6, lane = tid & 63;
    const int lr = lane & 15, hi = lane >> 4;
    const int wm2 = (wave & 1) * 32;   // S row offset for this wave
    const int wn2 = (wave >> 1) * 32;  // S col offset for this wave
    const int wnp = wave * 128;        // PV col offset for this wave

    // Q fragments: 2 m-tiles x 18 k-steps, persistent in registers.
    const u16* Qbase = Qp + ((long)h * T_TOK + qb + wm2) * 576;
    short8 qf[2][18];
#pragma unroll
    for (int mt = 0; mt < 2; mt++)
#pragma unroll
        for (int kk = 0; kk < 18; kk++)
            qf[mt][kk] = *(const short8*)(Qbase + (long)(mt * 16 + lr) * 576 + kk * 32 + hi * 8);

    floatx4 oacc[4][8] = {};
    float l_part[8] = {};

    for (int j = 0; j <= qt; j++) {
        const int jb = j * 64;
        // ---- S = Q-tile @ K-tile^T (K frags straight from global/L2) ----
        floatx4 sacc[2][2] = {};
        const u16* Kb0 = Kp + (long)(jb + wn2 + lr) * 576 + hi * 8;
        const u16* Kb1 = Kb0 + (long)16 * 576;
#pragma unroll
        for (int kk = 0; kk < 18; kk++) {
            short8 b0 = *(const short8*)(Kb0 + kk * 32);
            short8 b1 = *(const short8*)(Kb1 + kk * 32);
            sacc[0][0] = mfma16(qf[0][kk], b0, sacc[0][0]);
            sacc[0][1] = mfma16(qf[0][kk], b1, sacc[0][1]);
            sacc[1][0] = mfma16(qf[1][kk], b0, sacc[1][0]);
            sacc[1][1] = mfma16(qf[1][kk], b1, sacc[1][1]);
        }
        // ---- raw-exp softmax numerators, P -> LDS (bf16), l accumulation ----
        const int diag = (j == qt);
#pragma unroll
        for (int mt = 0; mt < 2; mt++) {
            const int qrow = wm2 + mt * 16 + hi * 4;
#pragma unroll
            for (int nt = 0; nt < 2; nt++) {
                const int kcol = wn2 + nt * 16 + lr;
#pragma unroll
                for (int r = 0; r < 4; r++) {
                    float p = (diag && kcol > qrow + r)
                                ? 0.0f
                                : exp2f(sacc[mt][nt][r] * ESCALE);
                    l_part[mt * 4 + r] += p;
                    Ps[(qrow + r) * P_LD + kcol] = f2bf(p);
                }
            }
        }
        __syncthreads();   // P visible
        // ---- O += P @ V  (V = cmpT tile, straight from global/L2) ----
#pragma unroll
        for (int kk = 0; kk < 2; kk++) {
            short8 pa[4];
#pragma unroll
            for (int mt = 0; mt < 4; mt++)
                pa[mt] = *(const short8*)((const u16*)Ps + (mt * 16 + lr) * P_LD + kk * 32 + hi * 8);
#pragma unroll
            for (int nt = 0; nt < 8; nt++) {
                const u16* vrow = cmpT + (long)(wnp + nt * 16 + lr) * T_TOK + jb + kk * 32 + hi * 8;
                short8 vb = *(const short8*)vrow;
#pragma unroll
                for (int mt = 0; mt < 4; mt++)
                    oacc[mt][nt] = mfma16(pa[mt], vb, oacc[mt][nt]);
            }
        }
        __syncthreads();   // P reads done before next overwrite
    }

    // ---- finalize row sums: reduce over the 16 col-holding lanes ----
#pragma unroll
    for (int i = 0; i < 8; i++) {
        float v = l_part[i];
        v += __shfl_xor(v, 1); v += __shfl_xor(v, 2);
        v += __shfl_xor(v, 4); v += __shfl_xor(v, 8);
        l_part[i] = v;
    }
    if (lr == 0) {
#pragma unroll
        for (int i = 0; i < 8; i++) {
            int row = wm2 + (i >> 2) * 16 + hi * 4 + (i & 3);
            ex[wave >> 1][row] = l_part[i];
        }
    }
    __syncthreads();
    // ---- O / l -> o_lat[h][t][512] ----
    const long obase = (long)h * T_TOK + qb;
#pragma unroll
    for (int mt = 0; mt < 4; mt++)
#pragma unroll
        for (int r = 0; r < 4; r++) {
            const int lrow = mt * 16 + hi * 4 + r;
            const float inv = 1.0f / (ex[0][lrow] + ex[1][lrow]);
#pragma unroll
            for (int nt = 0; nt < 8; nt++)
                o_lat[(obase + lrow) * 512 + wnp + nt * 16 + lr] =
                    f2bf(oacc[mt][nt][r] * inv);
        }
}

// f32 -> bf16 elementwise cast (n multiple of 4)
__global__ __launch_bounds__(256) void cast_bf16_k(const float* __restrict__ src,
                                                   u16* __restrict__ dst, long n)
{
    long i = ((long)blockIdx.x * 256 + threadIdx.x) * 4;
    if (i + 3 < n) {
        float4 v = *(const float4*)(src + i);
        u16x4 o = { f2bf(v.x), f2bf(v.y), f2bf(v.z), f2bf(v.w) };
        *(u16x4*)(dst + i) = o;
    }
}

// src (R x C) f32 row-major -> dst (Cpad x R) bf16 (transposed)
__global__ void transpose_cast(const float* __restrict__ src, u16* __restrict__ dst,
                               int R, int C, int Cpad)
{
    __shared__ float tile[32][33];
    const int cb = blockIdx.x * 32, rb = blockIdx.y * 32;
    for (int i = threadIdx.y; i < 32; i += 8) {
        int r = rb + i, c = cb + threadIdx.x;
        tile[i][threadIdx.x] = (r < R && c < C) ? src[(long)r * C + c] : 0.0f;
    }
    __syncthreads();
    for (int i = threadIdx.y; i < 32; i += 8) {
        int c = cb + i, r = rb + threadIdx.x;
        if (c < Cpad && r < R) dst[(long)c * R + r] = f2bf(tile[threadIdx.x][i]);
    }
}

// w_uv (KVL=512, H=32, DV=128) f32 -> dst[h][d][r] bf16 (per-head BT layout)
__global__ __launch_bounds__(256) void permute_wuv(const float* __restrict__ src,
                                                   u16* __restrict__ dst)
{
    int idx = blockIdx.x * 256 + threadIdx.x;
    int r = idx & 511;
    int hd = idx >> 9;
    int d = hd & 127, h = hd >> 7;
    dst[idx] = f2bf(src[(long)r * 4096 + h * 128 + d]);
}

// RMSNorm rows (bf16 in/out, fp32 accumulate)
__global__ __launch_bounds__(256) void rmsnorm_rows(const u16* __restrict__ in,
                                                    const float* __restrict__ gamma,
                                                    u16* __restrict__ out, int n, float invn)
{
    const long base = (long)blockIdx.x * n;
    const int tid = threadIdx.x, wave = tid >> 6, lane = tid & 63;
    __shared__ float red[4];
    float ss = 0.f;
    for (int i = tid; i < n; i += 256) { float x = bf2f(in[base + i]); ss += x * x; }
    for (int o = 32; o > 0; o >>= 1) ss += __shfl_xor(ss, o);
    if (lane == 0) red[wave] = ss;
    __syncthreads();
    ss = red[0] + red[1] + red[2] + red[3];
    const float r = rsqrtf(ss * invn + 1e-6f);
    for (int i = tid; i < n; i += 256) {
        float x = bf2f(in[base + i]);
        out[base + i] = f2bf(x * r * gamma[i]);
    }
}

// kv_a post: rmsnorm cols [0,512) -> Kp[:, :512] + compressed^T; rope cols
// [512,576) -> Kp[:, 512:576].  input ld 640 (padded), Kp ld 576.
__global__ __launch_bounds__(256) void kv_post(const u16* __restrict__ kva,
                                               const float* __restrict__ gamma,
                                               const int* __restrict__ pos,
                                               u16* __restrict__ Kp, u16* __restrict__ cmpT)
{
    const int t = blockIdx.x;
    const long base = (long)t * 640;
    const int tid = threadIdx.x, wave = tid >> 6, lane = tid & 63;
    __shared__ float red[4];
    float ss = 0.f;
    for (int i = tid; i < 512; i += 256) { float x = bf2f(kva[base + i]); ss += x * x; }
    for (int o = 32; o > 0; o >>= 1) ss += __shfl_xor(ss, o);
    if (lane == 0) red[wave] = ss;
    __syncthreads();
    ss = red[0] + red[1] + red[2] + red[3];
    const float r = rsqrtf(ss * (1.0f / 512.0f) + 1e-6f);
    for (int i = tid; i < 512; i += 256) {
        float x = bf2f(kva[base + i]) * r * gamma[i];
        u16 u = f2bf(x);
        Kp[(long)t * 576 + i] = u;
        cmpT[(long)i * T_TOK + t] = u;
    }
    if (tid < 32) {
        int j = tid;
        float invf = powf(10000.0f, -(float)j / 32.0f);
        float ang = (float)pos[t] * invf;
        float sn, cs;
        sincosf(ang, &sn, &cs);
        float x1 = bf2f(kva[base + 512 + 2 * j]);
        float x2 = bf2f(kva[base + 512 + 2 * j + 1]);
        Kp[(long)t * 576 + 512 + 2 * j]     = f2bf(x1 * cs - x2 * sn);
        Kp[(long)t * 576 + 512 + 2 * j + 1] = f2bf(x1 * sn + x2 * cs);
    }
}

// rope on q_rope part of q (T,H,192) -> Qp[h][t][512..576]
__global__ __launch_bounds__(256) void rope_q(const u16* __restrict__ q,
                                              const int* __restrict__ pos,
                                              u16* __restrict__ Qp)
{
    int idx = blockIdx.x * 256 + threadIdx.x;    // T*H*32
    int j = idx & 31;
    int h = (idx >> 5) & 31;
    int t = idx >> 10;
    float invf = powf(10000.0f, -(float)j / 32.0f);
    float ang = (float)pos[t] * invf;
    float sn, cs;
    sincosf(ang, &sn, &cs);
    long qb = (long)t * 6144 + h * 192 + 128 + 2 * j;
    float x1 = bf2f(q[qb]), x2 = bf2f(q[qb + 1]);
    long ob = (long)h * T_TOK * 576 + (long)t * 576 + 512 + 2 * j;
    Qp[ob]     = f2bf(x1 * cs - x2 * sn);
    Qp[ob + 1] = f2bf(x1 * sn + x2 * cs);
}

extern "C" void kernel_launch(void* const* d_in, const int* in_sizes, int n_in,
                              void* d_out, int out_size, void* d_ws, size_t ws_size,
                              hipStream_t stream)
{
    const float* hidden = (const float*)d_in[0];
    const int* positions = (const int*)d_in[1];
    const float* w_qa  = (const float*)d_in[2];
    const float* qa_g  = (const float*)d_in[3];
    const float* w_qb  = (const float*)d_in[4];
    const float* w_kva = (const float*)d_in[5];
    const float* kva_g = (const float*)d_in[6];
    const float* w_uk  = (const float*)d_in[7];
    const float* w_uv  = (const float*)d_in[8];
    const float* w_o   = (const float*)d_in[9];

    char* ws = (char*)d_ws;
    // o_lat (64 MB, all 32 heads) aliases the whole early region [0, 67108864):
    // qc/q/hid_bf/wqa_t/qc_raw are all dead before the flash kernel runs.
    u16* o_lat   = (u16*)(ws + 0);
    u16* qc      = (u16*)(ws + 0);
    u16* q       = (u16*)(ws + 6291456);
    u16* hid_bf  = (u16*)(ws + 31457280);
    u16* wqa_t   = (u16*)(ws + 48234496);
    u16* qc_raw  = (u16*)(ws + 60817408);
    u16* wqb_t   = (u16*)(ws + 67108864);
    u16* wkva_t  = (u16*)(ws + 85983232);
    u16* wuk_b   = (u16*)(ws + 91226112);
    u16* wuv_t   = (u16*)(ws + 95420416);
    u16* wo_t    = (u16*)(ws + 99614720);
    u16* kva_raw = (u16*)(ws + 133169152);
    u16* Kp      = (u16*)(ws + 135790592);
    u16* cmpT    = (u16*)(ws + 138149888);
    u16* Qp      = (u16*)(ws + 140247040);
    u16* o_v     = Qp;   // alias: Qp dead after attention

    // --- stage 0: casts / relayouts to bf16 ---------------------------------
    cast_bf16_k<<<8192, 256, 0, stream>>>(hidden, hid_bf, 8388608);
    transpose_cast<<<dim3(48, 128),  dim3(32, 8), 0, stream>>>(w_qa,  wqa_t,  4096, 1536, 1536);
    transpose_cast<<<dim3(192, 48),  dim3(32, 8), 0, stream>>>(w_qb,  wqb_t,  1536, 6144, 6144);
    transpose_cast<<<dim3(20, 128),  dim3(32, 8), 0, stream>>>(w_kva, wkva_t, 4096, 576,  640);
    cast_bf16_k<<<2048, 256, 0, stream>>>(w_uk, wuk_b, 2097152);
    permute_wuv<<<8192, 256, 0, stream>>>(w_uv, wuv_t);
    transpose_cast<<<dim3(128, 128), dim3(32, 8), 0, stream>>>(w_o,   wo_t,   4096, 4096, 4096);

    // --- stage 1: LoRA-A projections + norms --------------------------------
    gemm_bt<<<dim3(12, 16, 1), 256, 0, stream>>>(hid_bf, wqa_t, qc_raw,
        2048, 1536, 4096, 4096, 4096, 1536, 0, 0, 0, 1);
    gemm_bt<<<dim3(5, 16, 1), 256, 0, stream>>>(hid_bf, wkva_t, kva_raw,
        2048, 640, 4096, 4096, 4096, 640, 0, 0, 0, 1);
    rmsnorm_rows<<<2048, 256, 0, stream>>>(qc_raw, qa_g, qc, 1536, 1.0f / 1536.0f);
    kv_post<<<2048, 256, 0, stream>>>(kva_raw, kva_g, positions, Kp, cmpT);

    // --- stage 2: q up-projection, rope, per-head absorb --------------------
    gemm_bt<<<dim3(48, 16, 1), 256, 0, stream>>>(qc, wqb_t, q,
        2048, 6144, 1536, 1536, 1536, 6144, 0, 0, 0, 1);
    rope_q<<<8192, 256, 0, stream>>>(q, positions, Qp);
    gemm_bt<<<dim3(4, 16, 32), 256, 0, stream>>>(q, wuk_b, Qp,
        2048, 512, 128, 6144, 4096, 576, 192, 128, (long)2048 * 576, 1);

    // --- stage 3: fused causal attention (one dispatch) ---------------------
    flash_attn<<<dim3(32, 32), 256, 0, stream>>>(Qp, Kp, cmpT, o_lat);

    // --- stage 4: o_v and output projection ---------------------------------
    gemm_bt<<<dim3(1, 16, 32), 256, 0, stream>>>(o_lat, wuv_t, o_v,
        2048, 128, 512, 512, 512, 4096, (long)2048 * 512, 65536, 128, 1);
    gemm_bt<<<dim3(32, 16, 1), 256, 0, stream>>>(o_v, wo_t, d_out,
        2048, 4096, 4096, 4096, 4096, 4096, 0, 0, 0, 0);
}

// Round 4
// 954.383 us; speedup vs baseline: 2.0103x; 2.0103x over previous
//
#include <hip/hip_runtime.h>
#include <stdint.h>

typedef unsigned short u16;
typedef __attribute__((ext_vector_type(8))) short short8;
typedef __attribute__((ext_vector_type(4))) float floatx4;
typedef __attribute__((ext_vector_type(4))) unsigned short u16x4;

#define T_TOK 2048
#define NHEAD 32

__device__ __forceinline__ float bf2f(u16 u) { return __uint_as_float(((unsigned)u) << 16); }
__device__ __forceinline__ u16 f2bf(float f) {
    unsigned u = __float_as_uint(f);
    return (u16)((u + 0x7fffu + ((u >> 16) & 1u)) >> 16);
}

__device__ __forceinline__ floatx4 mfma16(short8 a, short8 b, floatx4 c) {
    return __builtin_amdgcn_mfma_f32_16x16x32_bf16(a, b, c, 0, 0, 0);
}

// ---------------------------------------------------------------------------
// Generic bf16 GEMM, C = A @ B^T.  A: M x K (lda), B: N x K (ldb), C: M x N.
// m97 structure: 128x128 tile, BK=32, global_load_lds width 16, 16x16x32 MFMA.
// ---------------------------------------------------------------------------
__global__ __launch_bounds__(256) void gemm_bt(
    const u16* __restrict__ A, const u16* __restrict__ B, void* __restrict__ Cp,
    int M, int N, int K, int lda, int ldb, int ldc,
    long sA, long sB, long sC, int c_bf16)
{
    __shared__ u16 As[128 * 32];
    __shared__ u16 Bs[128 * 32];
    const int z = blockIdx.z;
    A += (long)z * sA;
    B += (long)z * sB;
    const int tid  = threadIdx.x;
    const int wave = tid >> 6;
    const int lane = tid & 63;
    const long m0 = (long)blockIdx.y * 128;
    const long n0 = (long)blockIdx.x * 128;
    const int wm = (wave & 1) * 64;
    const int wn = (wave >> 1) * 64;
    const int lr = lane & 15;
    const int lk = (lane >> 4) * 8;

    const u16* Ag = A + (m0 + (tid >> 2)) * (long)lda + (tid & 3) * 8;
    const u16* Bg = B + (n0 + (tid >> 2)) * (long)ldb + (tid & 3) * 8;
    const long a64 = (long)64 * lda, b64 = (long)64 * ldb;

    floatx4 acc[4][4] = {};

    for (int k0 = 0; k0 < K; k0 += 32) {
        __syncthreads();
        __builtin_amdgcn_global_load_lds(
            (const __attribute__((address_space(1))) void*)(Ag + k0),
            (__attribute__((address_space(3))) void*)(As + wave * 512), 16, 0, 0);
        __builtin_amdgcn_global_load_lds(
            (const __attribute__((address_space(1))) void*)(Ag + k0 + a64),
            (__attribute__((address_space(3))) void*)(As + 2048 + wave * 512), 16, 0, 0);
        __builtin_amdgcn_global_load_lds(
            (const __attribute__((address_space(1))) void*)(Bg + k0),
            (__attribute__((address_space(3))) void*)(Bs + wave * 512), 16, 0, 0);
        __builtin_amdgcn_global_load_lds(
            (const __attribute__((address_space(1))) void*)(Bg + k0 + b64),
            (__attribute__((address_space(3))) void*)(Bs + 2048 + wave * 512), 16, 0, 0);
        __syncthreads();
        short8 af[4], bfr[4];
#pragma unroll
        for (int t = 0; t < 4; t++) {
            af[t]  = *(const short8*)&As[(wm + t * 16 + lr) * 32 + lk];
            bfr[t] = *(const short8*)&Bs[(wn + t * 16 + lr) * 32 + lk];
        }
#pragma unroll
        for (int mt = 0; mt < 4; mt++)
#pragma unroll
            for (int nt = 0; nt < 4; nt++)
                acc[mt][nt] = mfma16(af[mt], bfr[nt], acc[mt][nt]);
    }

    const int rbase = wm + (lane >> 4) * 4;
    if (c_bf16) {
        u16* C = (u16*)Cp + (long)z * sC;
#pragma unroll
        for (int mt = 0; mt < 4; mt++)
#pragma unroll
            for (int nt = 0; nt < 4; nt++)
#pragma unroll
                for (int r = 0; r < 4; r++) {
                    long row = m0 + rbase + mt * 16 + r;
                    long col = n0 + wn + nt * 16 + lr;
                    C[row * ldc + col] = f2bf(acc[mt][nt][r]);
                }
    } else {
        float* C = (float*)Cp + (long)z * sC;
#pragma unroll
        for (int mt = 0; mt < 4; mt++)
#pragma unroll
            for (int nt = 0; nt < 4; nt++)
#pragma unroll
                for (int r = 0; r < 4; r++) {
                    long row = m0 + rbase + mt * 16 + r;
                    long col = n0 + wn + nt * 16 + lr;
                    C[row * ldc + col] = acc[mt][nt][r];
                }
    }
}

// ---------------------------------------------------------------------------
// Fused causal MLA attention, v2.
// Block = (pair of q-tiles {qt, 31-qt}, head): perfectly balanced (66 j-chunks
// of 32 K-rows each).  4 waves; wave w owns S-rows w*16..w*16+16 and O-cols
// w*128..w*128+128.  K staged to LDS via global_load_lds; Q persistent in
// VGPRs; V (cmpT) direct from L2; raw-exp2 softmax, one divide at the end.
// ---------------------------------------------------------------------------
#define ESCALE 0.10411754f   // (1/sqrt(192)) * log2(e)

__global__ __launch_bounds__(256, 2) void flash_attn(
    const u16* __restrict__ Qp, const u16* __restrict__ Kp,
    const u16* __restrict__ cmpT, u16* __restrict__ o_lat)
{
    __shared__ u16 Ks[18 * 1024];   // [slab s=0..17][krow 0..31][ksub 0..31]
    __shared__ u16 Ps[64 * 40];     // P tile 64x32, padded ld 40 (16B-aligned rows)
    __shared__ float ex[64];

    const int h = blockIdx.y;
    const int tid = threadIdx.x, wave = tid >> 6, lane = tid & 63;
    const int lr = lane & 15, hi = lane >> 4;
    const int wnp = wave * 128;     // O column base for this wave

    // K-staging geometry: per round p (0..8), this thread covers
    // slab s = 2p + (wave>>1), krow = (wave&1)*16 + (lane>>2), ksub = (lane&3)*8
    const int st_row = ((wave & 1) << 4) + (lane >> 2);
    const int st_sub = (lane & 3) * 8;
    const int st_sb  = wave >> 1;
    u16* st_dst = Ks + (wave << 9) + lane * 8;

    for (int half = 0; half < 2; half++) {
        const int qt = half ? (31 - (int)blockIdx.x) : (int)blockIdx.x;
        const int qb = qt * 64;

        // persistent Q fragments: wave rows qb + wave*16 + lr, 18 k-slabs
        const u16* Qb = Qp + ((long)h * T_TOK + qb + wave * 16 + lr) * 576 + hi * 8;
        short8 qf[18];
#pragma unroll
        for (int s = 0; s < 18; s++) qf[s] = *(const short8*)(Qb + s * 32);

        floatx4 oacc[4][8] = {};
        float l_part[4] = {};

        const int nchunks = 2 * qt + 2;
        for (int c = 0; c < nchunks; c++) {
            const int jb = c * 32;
            // ---- stage K chunk (32 rows x 576) into LDS, async ----
            const u16* Ksrc = Kp + (long)(jb + st_row) * 576 + st_sub;
#pragma unroll
            for (int p = 0; p < 9; p++)
                __builtin_amdgcn_global_load_lds(
                    (const __attribute__((address_space(1))) void*)(Ksrc + (2 * p + st_sb) * 32),
                    (__attribute__((address_space(3))) void*)(st_dst + p * 2048), 16, 0, 0);
            __syncthreads();
            // ---- S = Q @ K^T : wave computes 16 q-rows x 32 k-cols ----
            floatx4 sacc[2] = {};
#pragma unroll
            for (int s = 0; s < 18; s++) {
                short8 b0 = *(const short8*)(Ks + s * 1024 + lr * 32 + hi * 8);
                short8 b1 = *(const short8*)(Ks + s * 1024 + (16 + lr) * 32 + hi * 8);
                sacc[0] = mfma16(qf[s], b0, sacc[0]);
                sacc[1] = mfma16(qf[s], b1, sacc[1]);
            }
            // ---- raw-exp2 softmax numerators -> P (LDS), l accumulation ----
            const int qg = qb + wave * 16 + hi * 4;
#pragma unroll
            for (int nt = 0; nt < 2; nt++) {
                const int kg = jb + nt * 16 + lr;
#pragma unroll
                for (int r = 0; r < 4; r++) {
                    float p = (kg <= qg + r) ? exp2f(sacc[nt][r] * ESCALE) : 0.0f;
                    l_part[r] += p;
                    Ps[(wave * 16 + hi * 4 + r) * 40 + nt * 16 + lr] = f2bf(p);
                }
            }
            __syncthreads();
            // ---- O += P @ V : P from LDS, V direct from L2-resident cmpT ----
            short8 pa[4];
#pragma unroll
            for (int mt = 0; mt < 4; mt++)
                pa[mt] = *(const short8*)(Ps + (mt * 16 + lr) * 40 + hi * 8);
#pragma unroll
            for (int nt = 0; nt < 8; nt++) {
                short8 vb = *(const short8*)(cmpT + (long)(wnp + nt * 16 + lr) * T_TOK + jb + hi * 8);
#pragma unroll
                for (int mt = 0; mt < 4; mt++)
                    oacc[mt][nt] = mfma16(pa[mt], vb, oacc[mt][nt]);
            }
        }

        // ---- finalize row sums (reduce over the 16 lr lanes) ----
#pragma unroll
        for (int r = 0; r < 4; r++) {
            float v = l_part[r];
            v += __shfl_xor(v, 1); v += __shfl_xor(v, 2);
            v += __shfl_xor(v, 4); v += __shfl_xor(v, 8);
            l_part[r] = v;
        }
        if (lr == 0) {
#pragma unroll
            for (int r = 0; r < 4; r++) ex[wave * 16 + hi * 4 + r] = l_part[r];
        }
        __syncthreads();
        // ---- O / l -> o_lat[h][t][512] ----
        const long obase = (long)h * T_TOK + qb;
#pragma unroll
        for (int mt = 0; mt < 4; mt++)
#pragma unroll
            for (int r = 0; r < 4; r++) {
                const int row = mt * 16 + hi * 4 + r;
                const float inv = 1.0f / ex[row];
#pragma unroll
                for (int nt = 0; nt < 8; nt++)
                    o_lat[(obase + row) * 512 + wnp + nt * 16 + lr] =
                        f2bf(oacc[mt][nt][r] * inv);
            }
        __syncthreads();
    }
}

// f32 -> bf16 elementwise cast (n multiple of 4)
__global__ __launch_bounds__(256) void cast_bf16_k(const float* __restrict__ src,
                                                   u16* __restrict__ dst, long n)
{
    long i = ((long)blockIdx.x * 256 + threadIdx.x) * 4;
    if (i + 3 < n) {
        float4 v = *(const float4*)(src + i);
        u16x4 o = { f2bf(v.x), f2bf(v.y), f2bf(v.z), f2bf(v.w) };
        *(u16x4*)(dst + i) = o;
    }
}

// src (R x C) f32 row-major -> dst (Cpad x R) bf16 (transposed)
__global__ void transpose_cast(const float* __restrict__ src, u16* __restrict__ dst,
                               int R, int C, int Cpad)
{
    __shared__ float tile[32][33];
    const int cb = blockIdx.x * 32, rb = blockIdx.y * 32;
    for (int i = threadIdx.y; i < 32; i += 8) {
        int r = rb + i, c = cb + threadIdx.x;
        tile[i][threadIdx.x] = (r < R && c < C) ? src[(long)r * C + c] : 0.0f;
    }
    __syncthreads();
    for (int i = threadIdx.y; i < 32; i += 8) {
        int c = cb + i, r = rb + threadIdx.x;
        if (c < Cpad && r < R) dst[(long)c * R + r] = f2bf(tile[threadIdx.x][i]);
    }
}

// w_uv (KVL=512, H=32, DV=128) f32 -> dst[h][d][r] bf16 (per-head BT layout)
__global__ __launch_bounds__(256) void permute_wuv(const float* __restrict__ src,
                                                   u16* __restrict__ dst)
{
    int idx = blockIdx.x * 256 + threadIdx.x;
    int r = idx & 511;
    int hd = idx >> 9;
    int d = hd & 127, h = hd >> 7;
    dst[idx] = f2bf(src[(long)r * 4096 + h * 128 + d]);
}

// RMSNorm rows (bf16 in/out, fp32 accumulate)
__global__ __launch_bounds__(256) void rmsnorm_rows(const u16* __restrict__ in,
                                                    const float* __restrict__ gamma,
                                                    u16* __restrict__ out, int n, float invn)
{
    const long base = (long)blockIdx.x * n;
    const int tid = threadIdx.x, wave = tid >> 6, lane = tid & 63;
    __shared__ float red[4];
    float ss = 0.f;
    for (int i = tid; i < n; i += 256) { float x = bf2f(in[base + i]); ss += x * x; }
    for (int o = 32; o > 0; o >>= 1) ss += __shfl_xor(ss, o);
    if (lane == 0) red[wave] = ss;
    __syncthreads();
    ss = red[0] + red[1] + red[2] + red[3];
    const float r = rsqrtf(ss * invn + 1e-6f);
    for (int i = tid; i < n; i += 256) {
        float x = bf2f(in[base + i]);
        out[base + i] = f2bf(x * r * gamma[i]);
    }
}

// kv_a post: rmsnorm cols [0,512) -> Kp[:, :512] + compressed^T; rope cols
// [512,576) -> Kp[:, 512:576].  input ld 640 (padded), Kp ld 576.
__global__ __launch_bounds__(256) void kv_post(const u16* __restrict__ kva,
                                               const float* __restrict__ gamma,
                                               const int* __restrict__ pos,
                                               u16* __restrict__ Kp, u16* __restrict__ cmpT)
{
    const int t = blockIdx.x;
    const long base = (long)t * 640;
    const int tid = threadIdx.x, wave = tid >> 6, lane = tid & 63;
    __shared__ float red[4];
    float ss = 0.f;
    for (int i = tid; i < 512; i += 256) { float x = bf2f(kva[base + i]); ss += x * x; }
    for (int o = 32; o > 0; o >>= 1) ss += __shfl_xor(ss, o);
    if (lane == 0) red[wave] = ss;
    __syncthreads();
    ss = red[0] + red[1] + red[2] + red[3];
    const float r = rsqrtf(ss * (1.0f / 512.0f) + 1e-6f);
    for (int i = tid; i < 512; i += 256) {
        float x = bf2f(kva[base + i]) * r * gamma[i];
        u16 u = f2bf(x);
        Kp[(long)t * 576 + i] = u;
        cmpT[(long)i * T_TOK + t] = u;
    }
    if (tid < 32) {
        int j = tid;
        float invf = powf(10000.0f, -(float)j / 32.0f);
        float ang = (float)pos[t] * invf;
        float sn, cs;
        sincosf(ang, &sn, &cs);
        float x1 = bf2f(kva[base + 512 + 2 * j]);
        float x2 = bf2f(kva[base + 512 + 2 * j + 1]);
        Kp[(long)t * 576 + 512 + 2 * j]     = f2bf(x1 * cs - x2 * sn);
        Kp[(long)t * 576 + 512 + 2 * j + 1] = f2bf(x1 * sn + x2 * cs);
    }
}

// rope on q_rope part of q (T,H,192) -> Qp[h][t][512..576]
__global__ __launch_bounds__(256) void rope_q(const u16* __restrict__ q,
                                              const int* __restrict__ pos,
                                              u16* __restrict__ Qp)
{
    int idx = blockIdx.x * 256 + threadIdx.x;    // T*H*32
    int j = idx & 31;
    int h = (idx >> 5) & 31;
    int t = idx >> 10;
    float invf = powf(10000.0f, -(float)j / 32.0f);
    float ang = (float)pos[t] * invf;
    float sn, cs;
    sincosf(ang, &sn, &cs);
    long qb = (long)t * 6144 + h * 192 + 128 + 2 * j;
    float x1 = bf2f(q[qb]), x2 = bf2f(q[qb + 1]);
    long ob = (long)h * T_TOK * 576 + (long)t * 576 + 512 + 2 * j;
    Qp[ob]     = f2bf(x1 * cs - x2 * sn);
    Qp[ob + 1] = f2bf(x1 * sn + x2 * cs);
}

extern "C" void kernel_launch(void* const* d_in, const int* in_sizes, int n_in,
                              void* d_out, int out_size, void* d_ws, size_t ws_size,
                              hipStream_t stream)
{
    const float* hidden = (const float*)d_in[0];
    const int* positions = (const int*)d_in[1];
    const float* w_qa  = (const float*)d_in[2];
    const float* qa_g  = (const float*)d_in[3];
    const float* w_qb  = (const float*)d_in[4];
    const float* w_kva = (const float*)d_in[5];
    const float* kva_g = (const float*)d_in[6];
    const float* w_uk  = (const float*)d_in[7];
    const float* w_uv  = (const float*)d_in[8];
    const float* w_o   = (const float*)d_in[9];

    char* ws = (char*)d_ws;
    // o_lat (64 MB, all 32 heads) aliases the whole early region [0, 67108864):
    // qc/q/hid_bf/wqa_t/qc_raw are all dead before the flash kernel runs.
    u16* o_lat   = (u16*)(ws + 0);
    u16* qc      = (u16*)(ws + 0);
    u16* q       = (u16*)(ws + 6291456);
    u16* hid_bf  = (u16*)(ws + 31457280);
    u16* wqa_t   = (u16*)(ws + 48234496);
    u16* qc_raw  = (u16*)(ws + 60817408);
    u16* wqb_t   = (u16*)(ws + 67108864);
    u16* wkva_t  = (u16*)(ws + 85983232);
    u16* wuk_b   = (u16*)(ws + 91226112);
    u16* wuv_t   = (u16*)(ws + 95420416);
    u16* wo_t    = (u16*)(ws + 99614720);
    u16* kva_raw = (u16*)(ws + 133169152);
    u16* Kp      = (u16*)(ws + 135790592);
    u16* cmpT    = (u16*)(ws + 138149888);
    u16* Qp      = (u16*)(ws + 140247040);
    u16* o_v     = Qp;   // alias: Qp dead after attention

    // --- stage 0: casts / relayouts to bf16 ---------------------------------
    cast_bf16_k<<<8192, 256, 0, stream>>>(hidden, hid_bf, 8388608);
    transpose_cast<<<dim3(48, 128),  dim3(32, 8), 0, stream>>>(w_qa,  wqa_t,  4096, 1536, 1536);
    transpose_cast<<<dim3(192, 48),  dim3(32, 8), 0, stream>>>(w_qb,  wqb_t,  1536, 6144, 6144);
    transpose_cast<<<dim3(20, 128),  dim3(32, 8), 0, stream>>>(w_kva, wkva_t, 4096, 576,  640);
    cast_bf16_k<<<2048, 256, 0, stream>>>(w_uk, wuk_b, 2097152);
    permute_wuv<<<8192, 256, 0, stream>>>(w_uv, wuv_t);
    transpose_cast<<<dim3(128, 128), dim3(32, 8), 0, stream>>>(w_o,   wo_t,   4096, 4096, 4096);

    // --- stage 1: LoRA-A projections + norms --------------------------------
    gemm_bt<<<dim3(12, 16, 1), 256, 0, stream>>>(hid_bf, wqa_t, qc_raw,
        2048, 1536, 4096, 4096, 4096, 1536, 0, 0, 0, 1);
    gemm_bt<<<dim3(5, 16, 1), 256, 0, stream>>>(hid_bf, wkva_t, kva_raw,
        2048, 640, 4096, 4096, 4096, 640, 0, 0, 0, 1);
    rmsnorm_rows<<<2048, 256, 0, stream>>>(qc_raw, qa_g, qc, 1536, 1.0f / 1536.0f);
    kv_post<<<2048, 256, 0, stream>>>(kva_raw, kva_g, positions, Kp, cmpT);

    // --- stage 2: q up-projection, rope, per-head absorb --------------------
    gemm_bt<<<dim3(48, 16, 1), 256, 0, stream>>>(qc, wqb_t, q,
        2048, 6144, 1536, 1536, 1536, 6144, 0, 0, 0, 1);
    rope_q<<<8192, 256, 0, stream>>>(q, positions, Qp);
    gemm_bt<<<dim3(4, 16, 32), 256, 0, stream>>>(q, wuk_b, Qp,
        2048, 512, 128, 6144, 4096, 576, 192, 128, (long)2048 * 576, 1);

    // --- stage 3: fused causal attention (one dispatch, balanced pairs) -----
    flash_attn<<<dim3(16, 32), 256, 0, stream>>>(Qp, Kp, cmpT, o_lat);

    // --- stage 4: o_v and output projection ---------------------------------
    gemm_bt<<<dim3(1, 16, 32), 256, 0, stream>>>(o_lat, wuv_t, o_v,
        2048, 128, 512, 512, 512, 4096, (long)2048 * 512, 65536, 128, 1);
    gemm_bt<<<dim3(32, 16, 1), 256, 0, stream>>>(o_v, wo_t, d_out,
        2048, 4096, 4096, 4096, 4096, 4096, 0, 0, 0, 0);
}